// Round 17
// baseline (428.828 us; speedup 1.0000x reference)
//
#include <hip/hip_runtime.h>

#define NPTS 8192
#define HDIM 64
#define KNN 16
#define LOG2E 1.4426950408889634f

typedef __attribute__((ext_vector_type(8))) short bf8_t;   // 8 bf16
typedef __attribute__((ext_vector_type(4))) float f4_t;    // MFMA C/D
#define MFMA16(a, b, c) __builtin_amdgcn_mfma_f32_16x16x32_bf16(a, b, c, 0, 0, 0)

__device__ __forceinline__ float fast_exp(float x) {
    float y = x * LOG2E;
    float r;
    asm volatile("v_exp_f32 %0, %1\n\ts_nop 1" : "=v"(r) : "v"(y));
    return r;
}
__device__ __forceinline__ unsigned short f2b(float x) {   // f32 -> bf16 RNE
    unsigned v = __float_as_uint(x);
    return (unsigned short)((v + 0x7FFFu + ((v >> 16) & 1u)) >> 16);
}

// ws layout: qw 0..4MB, kw 4..8MB, vw 8..12MB, frag 12MB..+24KB,
// knnIdx 12MB+32KB..+1MB, flags +16KB. ws >= 14.8 MB (established R12).
#define OFF_QW   0u
#define OFF_KW   (4u << 20)
#define OFF_VW   (8u << 20)
#define OFF_FRAG (12u << 20)
#define OFF_KNN  ((12u << 20) + 32768u)
#define OFF_FLAG ((13u << 20) + 32768u)

// ---------------------------------------------------------------------------
// prefrag: pack Wp2/Wt1/Wt2 into MFMA B-frag order (proven R11-R16).
// ---------------------------------------------------------------------------
__global__ void prefrag_kernel(const float* __restrict__ Wp2,
                               const float* __restrict__ Wt1,
                               const float* __restrict__ Wt2,
                               unsigned short* __restrict__ dst)
{
    int i = blockIdx.x * 256 + threadIdx.x;
    if (i >= 3 * 4096) return;
    int st = i >> 12, e = i & 4095;
    const float* W = (st == 0) ? Wp2 : (st == 1) ? Wt1 : Wt2;
    int k = e >> 6, n = e & 63;
    int s = k >> 5, quad = (k >> 3) & 3, j = k & 7;
    int t = n >> 4, l = quad * 16 + (n & 15);
    dst[st * 4096 + (s * 4 + t) * 512 + l * 8 + j] = f2b(W[e]);
}

// ---------------------------------------------------------------------------
// proj: LDS-staged weights (proven R16: W traffic /16).
// ---------------------------------------------------------------------------
__global__ __launch_bounds__(1024) void proj_kernel(
    const float* __restrict__ feat,
    const float* __restrict__ Wk, const float* __restrict__ bk,
    const float* __restrict__ Wq, const float* __restrict__ Wks,
    const float* __restrict__ Wv,
    float* __restrict__ qw, float* __restrict__ kw, float* __restrict__ vw)
{
    __shared__ __align__(16) float4 sW[4][1024];   // Wk, Wq, Wks, Wv (64 KB)
    int tid = threadIdx.x;
    sW[0][tid] = ((const float4*)Wk)[tid];
    sW[1][tid] = ((const float4*)Wq)[tid];
    sW[2][tid] = ((const float4*)Wks)[tid];
    sW[3][tid] = ((const float4*)Wv)[tid];
    __syncthreads();
    const float* sWk  = (const float*)sW[0];
    const float* sWq  = (const float*)sW[1];
    const float* sWks = (const float*)sW[2];
    const float* sWv  = (const float*)sW[3];

    int w = tid >> 6, lane = tid & 63;
    int p = blockIdx.x * 16 + w;
    float f = feat[(size_t)p * HDIM + lane];
    float x = bk[lane];
    #pragma unroll 8
    for (int c = 0; c < 64; ++c) x += __shfl(f, c) * sWk[c * 64 + lane];
    float q = 0.f, k = 0.f, v = 0.f;
    #pragma unroll 8
    for (int c = 0; c < 64; ++c) {
        float xc = __shfl(x, c);
        q += xc * sWq[c * 64 + lane];
        k += xc * sWks[c * 64 + lane];
        v += xc * sWv[c * 64 + lane];
    }
    qw[(size_t)p * HDIM + lane] = q;
    kw[(size_t)p * HDIM + lane] = k;
    vw[(size_t)p * HDIM + lane] = v;
}

// ---------------------------------------------------------------------------
// knn4 v2: redo EXCISED into knnfix_kernel (kills eh/ei register pressure ->
// R16's VGPR=60 implied hot-loop scratch spills); __launch_bounds__(256,4)
// caps at 128 VGPR so all arrays stay in registers. Scan/insert/merge math
// bit-identical to R16. Writes per-wave 4-bit fail mask (unconditional).
// ---------------------------------------------------------------------------
__global__ __launch_bounds__(256, 4) void knn4_kernel(
    const float* __restrict__ xyzp, int* __restrict__ knnIdx,
    int* __restrict__ flagw)
{
    int w = threadIdx.x >> 6, lane = threadIdx.x & 63;
    int wid = blockIdx.x * 4 + w;            // 0..4095
    int pbase = wid * 4;
    int b = pbase >> 13;
    int nbase = pbase & (NPTS - 1);
    const float4* xb4 = (const float4*)xyzp + (size_t)b * NPTS;

    float qx[4], qy[4], qz[4], qs[4];
    #pragma unroll
    for (int qi = 0; qi < 4; ++qi) {
        float4 s = xb4[nbase + qi];
        qx[qi] = s.x; qy[qi] = s.y; qz[qi] = s.z;
        qs[qi] = s.x * s.x + s.y * s.y + s.z * s.z;
    }

    float dh[4][4]; int ih[4][4];
    #pragma unroll
    for (int qi = 0; qi < 4; ++qi)
        #pragma unroll
        for (int j = 0; j < 4; ++j) { dh[qi][j] = 3.4e38f; ih[qi][j] = 0x7fffffff; }

    for (int t = 0; t < NPTS / 256; ++t) {           // 32 iters x 4 loads (R16)
        float4 c[4];
        #pragma unroll
        for (int u = 0; u < 4; ++u)
            c[u] = xb4[(t * 4 + u) * 64 + lane];
        #pragma unroll
        for (int u = 0; u < 4; ++u) {
            int m = (t * 4 + u) * 64 + lane;
            float cs = c[u].x * c[u].x + c[u].y * c[u].y + c[u].z * c[u].z;
            #pragma unroll
            for (int qi = 0; qi < 4; ++qi) {
                float d = qs[qi] + cs
                        - 2.0f * (qx[qi] * c[u].x + qy[qi] * c[u].y + qz[qi] * c[u].z);
                if (d < dh[qi][3]) {     // strict <: ties keep lower index
                    dh[qi][3] = d; ih[qi][3] = m;
                    #pragma unroll
                    for (int j = 3; j >= 1; --j)
                        if (dh[qi][j] < dh[qi][j - 1]) {
                            float td = dh[qi][j]; dh[qi][j] = dh[qi][j - 1]; dh[qi][j - 1] = td;
                            int ti = ih[qi][j]; ih[qi][j] = ih[qi][j - 1]; ih[qi][j - 1] = ti;
                        }
                }
            }
        }
    }

    int failmask = 0;
    #pragma unroll
    for (int qi = 0; qi < 4; ++qi) {
        int mynb = 0, head = 0;
        #pragma unroll 1
        for (int r = 0; r < KNN; ++r) {
            float d = dh[qi][0]; int i = ih[qi][0];
            #pragma unroll
            for (int s = 1; s < 64; s <<= 1) {
                float d2 = __shfl_xor(d, s); int i2 = __shfl_xor(i, s);
                if (d2 < d || (d2 == d && i2 < i)) { d = d2; i = i2; }
            }
            if (lane == r) mynb = i;
            if (ih[qi][0] == i) {
                dh[qi][0] = dh[qi][1]; ih[qi][0] = ih[qi][1];
                dh[qi][1] = dh[qi][2]; ih[qi][1] = ih[qi][2];
                dh[qi][2] = dh[qi][3]; ih[qi][2] = ih[qi][3];
                dh[qi][3] = 3.4e38f; ih[qi][3] = 0x7fffffff;
                ++head;
            }
        }
        if (__any(head >= 4)) failmask |= (1 << qi);   // defer to fixup
        mynb = min(max(mynb, 0), NPTS - 1);
        if (lane < KNN) knnIdx[(size_t)(pbase + qi) * KNN + lane] = mynb;
    }
    if (lane == 0) flagw[wid] = failmask;              // unconditional write
}

// ---------------------------------------------------------------------------
// knnfix: ~0.7%/query tail — proven 16-deep scan + merge, rewrites knnIdx.
// Exactness: any lane holding >=4 of the true top-16 triggers head>=4 in
// knn4 (same argument as R13-R16 redo), so flagged queries cover all cases.
// ---------------------------------------------------------------------------
__global__ __launch_bounds__(256) void knnfix_kernel(
    const float* __restrict__ xyzp, const int* __restrict__ flagw,
    int* __restrict__ knnIdx)
{
    int w = threadIdx.x >> 6, lane = threadIdx.x & 63;
    int wid = blockIdx.x * 4 + w;
    int failmask = flagw[wid];
    if (failmask == 0) return;
    int pbase = wid * 4;
    int b = pbase >> 13;
    int nbase = pbase & (NPTS - 1);
    const float4* xb4 = (const float4*)xyzp + (size_t)b * NPTS;

    #pragma unroll 1
    for (int qi = 0; qi < 4; ++qi) {
        if (!((failmask >> qi) & 1)) continue;
        float4 s = xb4[nbase + qi];
        float qx = s.x, qy = s.y, qz = s.z;
        float qs = qx * qx + qy * qy + qz * qz;
        float eh[16]; int ei[16];
        #pragma unroll
        for (int j = 0; j < 16; ++j) { eh[j] = 3.4e38f; ei[j] = 0x7fffffff; }
        for (int t = 0; t < NPTS / 64; ++t) {
            int m = t * 64 + lane;
            float4 c4 = xb4[m];
            float cs = c4.x * c4.x + c4.y * c4.y + c4.z * c4.z;
            float d = qs + cs - 2.0f * (qx * c4.x + qy * c4.y + qz * c4.z);
            if (d < eh[15]) {
                eh[15] = d; ei[15] = m;
                #pragma unroll
                for (int j = 15; j >= 1; --j)
                    if (eh[j] < eh[j - 1]) {
                        float td = eh[j]; eh[j] = eh[j - 1]; eh[j - 1] = td;
                        int ti = ei[j]; ei[j] = ei[j - 1]; ei[j - 1] = ti;
                    }
            }
        }
        int mynb = 0;
        #pragma unroll 1
        for (int r = 0; r < KNN; ++r) {
            float d = eh[0]; int i = ei[0];
            #pragma unroll
            for (int s2 = 1; s2 < 64; s2 <<= 1) {
                float d2 = __shfl_xor(d, s2); int i2 = __shfl_xor(i, s2);
                if (d2 < d || (d2 == d && i2 < i)) { d = d2; i = i2; }
            }
            if (lane == r) mynb = i;
            if (ei[0] == i) {
                #pragma unroll
                for (int j = 0; j < 15; ++j) { eh[j] = eh[j + 1]; ei[j] = ei[j + 1]; }
                eh[15] = 3.4e38f; ei[15] = 0x7fffffff;
            }
        }
        mynb = min(max(mynb, 0), NPTS - 1);
        if (lane < KNN) knnIdx[(size_t)(pbase + qi) * KNN + lane] = mynb;
    }
}

// ---------------------------------------------------------------------------
// main: MFMA per-neighbor MLPs consuming knnIdx (proven verbatim R12/R14-R16).
// ---------------------------------------------------------------------------
__global__ __launch_bounds__(256) void LocalTransformer_80513456931527_kernel(
    const float* __restrict__ xyzp, const float* __restrict__ features,
    const float* __restrict__ Wp1,  const float* __restrict__ bp1,
    const float* __restrict__ bp2,  const float* __restrict__ bt1,
    const float* __restrict__ bt2,
    const float* __restrict__ Wa,   const float* __restrict__ ba,
    const float* __restrict__ qw, const float* __restrict__ kw,
    const float* __restrict__ vw,
    const unsigned short* __restrict__ fragw,
    const int* __restrict__ knnIdx,
    float* __restrict__ out)
{
    __shared__ __align__(16) float sBounce[4][16 * 68 + 4];

    int tid = threadIdx.x, w = tid >> 6, lane = tid & 63;
    int p = blockIdx.x * 4 + w;
    int b = p >> 13;
    float* bb = sBounce[w];

    int quad = lane >> 4, l15 = lane & 15;
    int mynb = knnIdx[(size_t)p * KNN + l15];
    mynb = min(max(mynb, 0), NPTS - 1);
    int nb_a = mynb;
    int nbm[4];
    #pragma unroll
    for (int r = 0; r < 4; ++r) nbm[r] = __shfl(mynb, quad * 4 + r);

    const float4 xq4 = *(const float4*)(xyzp + (size_t)p * 4);
    const float4 xn4 = *(const float4*)(xyzp + ((size_t)b * NPTS + nb_a) * 4);
    float rel0 = xq4.x - xn4.x, rel1 = xq4.y - xn4.y;
    float rel2 = xq4.z - xn4.z, rel3 = xq4.w - xn4.w;

    bf8_t pe1f[2];
    #pragma unroll
    for (int s = 0; s < 2; ++s) {
        int hb = s * 32 + quad * 8;
        float W0[8], W1[8], W2[8], W3[8], Bb[8];
        *(float4*)&W0[0] = *(const float4*)(Wp1 +       hb);
        *(float4*)&W0[4] = *(const float4*)(Wp1 +       hb + 4);
        *(float4*)&W1[0] = *(const float4*)(Wp1 +  64 + hb);
        *(float4*)&W1[4] = *(const float4*)(Wp1 +  64 + hb + 4);
        *(float4*)&W2[0] = *(const float4*)(Wp1 + 128 + hb);
        *(float4*)&W2[4] = *(const float4*)(Wp1 + 128 + hb + 4);
        *(float4*)&W3[0] = *(const float4*)(Wp1 + 192 + hb);
        *(float4*)&W3[4] = *(const float4*)(Wp1 + 192 + hb + 4);
        *(float4*)&Bb[0] = *(const float4*)(bp1 + hb);
        *(float4*)&Bb[4] = *(const float4*)(bp1 + hb + 4);
        #pragma unroll
        for (int j = 0; j < 8; ++j) {
            float a = Bb[j] + rel0 * W0[j] + rel1 * W1[j]
                            + rel2 * W2[j] + rel3 * W3[j];
            pe1f[s][j] = (short)f2b(fmaxf(a, 0.f));
        }
    }

    const bf8_t* BW = (const bf8_t*)fragw;
    f4_t pe2c[4];
    #pragma unroll
    for (int t = 0; t < 4; ++t) {
        f4_t acc = {0.f, 0.f, 0.f, 0.f};
        acc = MFMA16(pe1f[0], BW[0 * 512 + (0 * 4 + t) * 64 + lane], acc);
        acc = MFMA16(pe1f[1], BW[0 * 512 + (1 * 4 + t) * 64 + lane], acc);
        float bias = bp2[t * 16 + l15];
        #pragma unroll
        for (int r = 0; r < 4; ++r) acc[r] += bias;
        pe2c[t] = acc;
    }

    f4_t ainc[4], vpec[4];
    #pragma unroll
    for (int t = 0; t < 4; ++t) {
        float qv = qw[(size_t)p * HDIM + t * 16 + l15];
        #pragma unroll
        for (int r = 0; r < 4; ++r) {
            size_t nbo = ((size_t)b * NPTS + nbm[r]) * HDIM + t * 16 + l15;
            ainc[t][r] = qv - kw[nbo] + pe2c[t][r];
            vpec[t][r] = vw[nbo] + pe2c[t][r];
        }
    }

    #pragma unroll
    for (int t = 0; t < 4; ++t)
        #pragma unroll
        for (int r = 0; r < 4; ++r)
            bb[(quad * 4 + r) * 68 + t * 16 + l15] = ainc[t][r];
    asm volatile("s_waitcnt lgkmcnt(0)" ::: "memory");
    bf8_t af[2];
    #pragma unroll
    for (int s = 0; s < 2; ++s) {
        float tmp[8];
        *(float4*)&tmp[0] = *(const float4*)&bb[l15 * 68 + s * 32 + quad * 8];
        *(float4*)&tmp[4] = *(const float4*)&bb[l15 * 68 + s * 32 + quad * 8 + 4];
        #pragma unroll
        for (int j = 0; j < 8; ++j) af[s][j] = (short)f2b(tmp[j]);
    }

    f4_t t1c[4];
    #pragma unroll
    for (int t = 0; t < 4; ++t) {
        f4_t acc = {0.f, 0.f, 0.f, 0.f};
        acc = MFMA16(af[0], BW[1 * 512 + (0 * 4 + t) * 64 + lane], acc);
        acc = MFMA16(af[1], BW[1 * 512 + (1 * 4 + t) * 64 + lane], acc);
        float bias = bt1[t * 16 + l15];
        #pragma unroll
        for (int r = 0; r < 4; ++r) t1c[t][r] = fmaxf(acc[r] + bias, 0.f);
    }

    asm volatile("s_waitcnt lgkmcnt(0)" ::: "memory");
    #pragma unroll
    for (int t = 0; t < 4; ++t)
        #pragma unroll
        for (int r = 0; r < 4; ++r)
            bb[(quad * 4 + r) * 68 + t * 16 + l15] = t1c[t][r];
    asm volatile("s_waitcnt lgkmcnt(0)" ::: "memory");
    bf8_t tf[2];
    #pragma unroll
    for (int s = 0; s < 2; ++s) {
        float tmp[8];
        *(float4*)&tmp[0] = *(const float4*)&bb[l15 * 68 + s * 32 + quad * 8];
        *(float4*)&tmp[4] = *(const float4*)&bb[l15 * 68 + s * 32 + quad * 8 + 4];
        #pragma unroll
        for (int j = 0; j < 8; ++j) tf[s][j] = (short)f2b(tmp[j]);
    }

    f4_t lgc[4];
    #pragma unroll
    for (int t = 0; t < 4; ++t) {
        f4_t acc = {0.f, 0.f, 0.f, 0.f};
        acc = MFMA16(tf[0], BW[2 * 512 + (0 * 4 + t) * 64 + lane], acc);
        acc = MFMA16(tf[1], BW[2 * 512 + (1 * 4 + t) * 64 + lane], acc);
        float bias = bt2[t * 16 + l15];
        #pragma unroll
        for (int r = 0; r < 4; ++r) lgc[t][r] = (acc[r] + bias) * 0.125f;
    }

    float res[4];
    #pragma unroll
    for (int t = 0; t < 4; ++t) {
        float m0 = fmaxf(fmaxf(lgc[t][0], lgc[t][1]), fmaxf(lgc[t][2], lgc[t][3]));
        m0 = fmaxf(m0, __shfl_xor(m0, 16));
        m0 = fmaxf(m0, __shfl_xor(m0, 32));
        float e0 = fast_exp(lgc[t][0] - m0), e1 = fast_exp(lgc[t][1] - m0);
        float e2 = fast_exp(lgc[t][2] - m0), e3 = fast_exp(lgc[t][3] - m0);
        float sl = e0 + e1 + e2 + e3;
        float rl = e0 * vpec[t][0] + e1 * vpec[t][1]
                 + e2 * vpec[t][2] + e3 * vpec[t][3];
        sl += __shfl_xor(sl, 16); sl += __shfl_xor(sl, 32);
        rl += __shfl_xor(rl, 16); rl += __shfl_xor(rl, 32);
        res[t] = rl / sl;
    }

    float rh = (quad == 0) ? res[0] : (quad == 1) ? res[1]
             : (quad == 2) ? res[2] : res[3];
    float f = features[(size_t)p * HDIM + lane];
    float o = ba[lane];
    #pragma unroll 8
    for (int c = 0; c < 64; ++c) o += __shfl(rh, c) * Wa[c * 64 + lane];
    out[(size_t)p * HDIM + lane] = o + f;
}

// ---------------------------------------------------------------------------
extern "C" void kernel_launch(void* const* d_in, const int* in_sizes, int n_in,
                              void* d_out, int out_size, void* d_ws, size_t ws_size,
                              hipStream_t stream)
{
    (void)in_sizes; (void)n_in; (void)out_size; (void)ws_size;
    const float* xyzp     = (const float*)d_in[0];
    const float* features = (const float*)d_in[1];
    const float* Wk  = (const float*)d_in[2];
    const float* bk  = (const float*)d_in[3];
    const float* Wq  = (const float*)d_in[4];
    const float* Wks = (const float*)d_in[5];
    const float* Wv  = (const float*)d_in[6];
    const float* Wp1 = (const float*)d_in[7];
    const float* bp1 = (const float*)d_in[8];
    const float* Wp2 = (const float*)d_in[9];
    const float* bp2 = (const float*)d_in[10];
    const float* Wt1 = (const float*)d_in[11];
    const float* bt1 = (const float*)d_in[12];
    const float* Wt2 = (const float*)d_in[13];
    const float* bt2 = (const float*)d_in[14];
    const float* Wa  = (const float*)d_in[15];
    const float* ba  = (const float*)d_in[16];
    float* out = (float*)d_out;
    char* ws = (char*)d_ws;

    float* qw = (float*)(ws + OFF_QW);
    float* kw = (float*)(ws + OFF_KW);
    float* vw = (float*)(ws + OFF_VW);
    unsigned short* fragw = (unsigned short*)(ws + OFF_FRAG);
    int* knnIdx = (int*)(ws + OFF_KNN);
    int* flagw  = (int*)(ws + OFF_FLAG);

    prefrag_kernel<<<48, 256, 0, stream>>>(Wp2, Wt1, Wt2, fragw);
    proj_kernel<<<(2 * NPTS) / 16, 1024, 0, stream>>>(
        features, Wk, bk, Wq, Wks, Wv, qw, kw, vw);
    knn4_kernel<<<(2 * NPTS) / 16, 256, 0, stream>>>(xyzp, knnIdx, flagw);
    knnfix_kernel<<<(2 * NPTS) / 16, 256, 0, stream>>>(xyzp, flagw, knnIdx);
    LocalTransformer_80513456931527_kernel<<<(2 * NPTS) / 4, 256, 0, stream>>>(
        xyzp, features, Wp1, bp1, bp2, bt1, bt2, Wa, ba,
        qw, kw, vw, fragw, knnIdx, out);
}

// Round 18
// 380.590 us; speedup vs baseline: 1.1267x; 1.1267x over previous
//
#include <hip/hip_runtime.h>

#define NPTS 8192
#define HDIM 64
#define KNN 16
#define LOG2E 1.4426950408889634f

typedef __attribute__((ext_vector_type(8))) short bf8_t;   // 8 bf16
typedef __attribute__((ext_vector_type(4))) float f4_t;    // MFMA C/D
#define MFMA16(a, b, c) __builtin_amdgcn_mfma_f32_16x16x32_bf16(a, b, c, 0, 0, 0)

__device__ __forceinline__ float fast_exp(float x) {
    float y = x * LOG2E;
    float r;
    asm volatile("v_exp_f32 %0, %1\n\ts_nop 1" : "=v"(r) : "v"(y));
    return r;
}
__device__ __forceinline__ unsigned short f2b(float x) {   // f32 -> bf16 RNE
    unsigned v = __float_as_uint(x);
    return (unsigned short)((v + 0x7FFFu + ((v >> 16) & 1u)) >> 16);
}

// ws layout: qw 0..4MB, kw 4..8MB, vw 8..12MB, frag 12MB..+24KB,
// knnIdx 12MB+32KB..+1MB, fix counter/worklist at 13MB+32KB.
#define OFF_QW   0u
#define OFF_KW   (4u << 20)
#define OFF_VW   (8u << 20)
#define OFF_FRAG (12u << 20)
#define OFF_KNN  ((12u << 20) + 32768u)
#define OFF_FIX  ((13u << 20) + 32768u)   // [0]=count, [16..] = query ids

// ---------------------------------------------------------------------------
// prefrag: pack Wp2/Wt1/Wt2 into MFMA B-frag order (proven R11-R17).
// ---------------------------------------------------------------------------
__global__ void prefrag_kernel(const float* __restrict__ Wp2,
                               const float* __restrict__ Wt1,
                               const float* __restrict__ Wt2,
                               unsigned short* __restrict__ dst)
{
    int i = blockIdx.x * 256 + threadIdx.x;
    if (i >= 3 * 4096) return;
    int st = i >> 12, e = i & 4095;
    const float* W = (st == 0) ? Wp2 : (st == 1) ? Wt1 : Wt2;
    int k = e >> 6, n = e & 63;
    int s = k >> 5, quad = (k >> 3) & 3, j = k & 7;
    int t = n >> 4, l = quad * 16 + (n & 15);
    dst[st * 4096 + (s * 4 + t) * 512 + l * 8 + j] = f2b(W[e]);
}

// ---------------------------------------------------------------------------
// proj: LDS-staged weights (proven R16/R17).
// ---------------------------------------------------------------------------
__global__ __launch_bounds__(1024) void proj_kernel(
    const float* __restrict__ feat,
    const float* __restrict__ Wk, const float* __restrict__ bk,
    const float* __restrict__ Wq, const float* __restrict__ Wks,
    const float* __restrict__ Wv,
    float* __restrict__ qw, float* __restrict__ kw, float* __restrict__ vw)
{
    __shared__ __align__(16) float4 sW[4][1024];   // Wk, Wq, Wks, Wv (64 KB)
    int tid = threadIdx.x;
    sW[0][tid] = ((const float4*)Wk)[tid];
    sW[1][tid] = ((const float4*)Wq)[tid];
    sW[2][tid] = ((const float4*)Wks)[tid];
    sW[3][tid] = ((const float4*)Wv)[tid];
    __syncthreads();
    const float* sWk  = (const float*)sW[0];
    const float* sWq  = (const float*)sW[1];
    const float* sWks = (const float*)sW[2];
    const float* sWv  = (const float*)sW[3];

    int w = tid >> 6, lane = tid & 63;
    int p = blockIdx.x * 16 + w;
    float f = feat[(size_t)p * HDIM + lane];
    float x = bk[lane];
    #pragma unroll 8
    for (int c = 0; c < 64; ++c) x += __shfl(f, c) * sWk[c * 64 + lane];
    float q = 0.f, k = 0.f, v = 0.f;
    #pragma unroll 8
    for (int c = 0; c < 64; ++c) {
        float xc = __shfl(x, c);
        q += xc * sWq[c * 64 + lane];
        k += xc * sWks[c * 64 + lane];
        v += xc * sWv[c * 64 + lane];
    }
    qw[(size_t)p * HDIM + lane] = q;
    kw[(size_t)p * HDIM + lane] = k;
    vw[(size_t)p * HDIM + lane] = v;
}

// ---------------------------------------------------------------------------
// knn4 (hot loop IDENTICAL to R17's proven 155 us / VGPR 40 version).
// Change: flagged queries append to a compacted worklist (device atomics)
// instead of a per-wave flag array.
// ---------------------------------------------------------------------------
__global__ __launch_bounds__(256, 4) void knn4_kernel(
    const float* __restrict__ xyzp, int* __restrict__ knnIdx,
    int* __restrict__ fix)
{
    int w = threadIdx.x >> 6, lane = threadIdx.x & 63;
    int wid = blockIdx.x * 4 + w;            // 0..4095
    int pbase = wid * 4;
    int b = pbase >> 13;
    int nbase = pbase & (NPTS - 1);
    const float4* xb4 = (const float4*)xyzp + (size_t)b * NPTS;

    float qx[4], qy[4], qz[4], qs[4];
    #pragma unroll
    for (int qi = 0; qi < 4; ++qi) {
        float4 s = xb4[nbase + qi];
        qx[qi] = s.x; qy[qi] = s.y; qz[qi] = s.z;
        qs[qi] = s.x * s.x + s.y * s.y + s.z * s.z;
    }

    float dh[4][4]; int ih[4][4];
    #pragma unroll
    for (int qi = 0; qi < 4; ++qi)
        #pragma unroll
        for (int j = 0; j < 4; ++j) { dh[qi][j] = 3.4e38f; ih[qi][j] = 0x7fffffff; }

    for (int t = 0; t < NPTS / 256; ++t) {           // 32 iters x 4 loads
        float4 c[4];
        #pragma unroll
        for (int u = 0; u < 4; ++u)
            c[u] = xb4[(t * 4 + u) * 64 + lane];
        #pragma unroll
        for (int u = 0; u < 4; ++u) {
            int m = (t * 4 + u) * 64 + lane;
            float cs = c[u].x * c[u].x + c[u].y * c[u].y + c[u].z * c[u].z;
            #pragma unroll
            for (int qi = 0; qi < 4; ++qi) {
                float d = qs[qi] + cs
                        - 2.0f * (qx[qi] * c[u].x + qy[qi] * c[u].y + qz[qi] * c[u].z);
                if (d < dh[qi][3]) {     // strict <: ties keep lower index
                    dh[qi][3] = d; ih[qi][3] = m;
                    #pragma unroll
                    for (int j = 3; j >= 1; --j)
                        if (dh[qi][j] < dh[qi][j - 1]) {
                            float td = dh[qi][j]; dh[qi][j] = dh[qi][j - 1]; dh[qi][j - 1] = td;
                            int ti = ih[qi][j]; ih[qi][j] = ih[qi][j - 1]; ih[qi][j - 1] = ti;
                        }
                }
            }
        }
    }

    int failmask = 0;
    #pragma unroll
    for (int qi = 0; qi < 4; ++qi) {
        int mynb = 0, head = 0;
        #pragma unroll 1
        for (int r = 0; r < KNN; ++r) {
            float d = dh[qi][0]; int i = ih[qi][0];
            #pragma unroll
            for (int s = 1; s < 64; s <<= 1) {
                float d2 = __shfl_xor(d, s); int i2 = __shfl_xor(i, s);
                if (d2 < d || (d2 == d && i2 < i)) { d = d2; i = i2; }
            }
            if (lane == r) mynb = i;
            if (ih[qi][0] == i) {
                dh[qi][0] = dh[qi][1]; ih[qi][0] = ih[qi][1];
                dh[qi][1] = dh[qi][2]; ih[qi][1] = ih[qi][2];
                dh[qi][2] = dh[qi][3]; ih[qi][2] = ih[qi][3];
                dh[qi][3] = 3.4e38f; ih[qi][3] = 0x7fffffff;
                ++head;
            }
        }
        if (__any(head >= 4)) failmask |= (1 << qi);
        mynb = min(max(mynb, 0), NPTS - 1);
        if (lane < KNN) knnIdx[(size_t)(pbase + qi) * KNN + lane] = mynb;
    }
    if (lane == 0 && failmask) {         // ~0.7%/query: append to worklist
        #pragma unroll
        for (int qi = 0; qi < 4; ++qi)
            if ((failmask >> qi) & 1) {
                int slot = atomicAdd(&fix[0], 1);
                fix[16 + slot] = pbase + qi;
            }
    }
}

// ---------------------------------------------------------------------------
// knnfix v2: FIXED 64-block grid, grid-strides the compacted worklist.
// Empty list -> read count + exit (~2 us). Proven 16-deep rescan per entry.
// Exactness: same head>=4 coverage argument as R13-R17.
// ---------------------------------------------------------------------------
__global__ __launch_bounds__(256) void knnfix_kernel(
    const float* __restrict__ xyzp, const int* __restrict__ fix,
    int* __restrict__ knnIdx)
{
    int w = threadIdx.x >> 6, lane = threadIdx.x & 63;
    int gw = blockIdx.x * 4 + w;             // 0..255
    int ncnt = fix[0];
    #pragma unroll 1
    for (int e = gw; e < ncnt; e += 256) {
        int p = fix[16 + e];                 // global point id 0..16383
        int b = p >> 13, nq = p & (NPTS - 1);
        const float4* xb4 = (const float4*)xyzp + (size_t)b * NPTS;
        float4 s = xb4[nq];
        float qx = s.x, qy = s.y, qz = s.z;
        float qs = qx * qx + qy * qy + qz * qz;
        float eh[16]; int ei[16];
        #pragma unroll
        for (int j = 0; j < 16; ++j) { eh[j] = 3.4e38f; ei[j] = 0x7fffffff; }
        for (int t = 0; t < NPTS / 64; ++t) {
            int m = t * 64 + lane;
            float4 c4 = xb4[m];
            float cs = c4.x * c4.x + c4.y * c4.y + c4.z * c4.z;
            float d = qs + cs - 2.0f * (qx * c4.x + qy * c4.y + qz * c4.z);
            if (d < eh[15]) {
                eh[15] = d; ei[15] = m;
                #pragma unroll
                for (int j = 15; j >= 1; --j)
                    if (eh[j] < eh[j - 1]) {
                        float td = eh[j]; eh[j] = eh[j - 1]; eh[j - 1] = td;
                        int ti = ei[j]; ei[j] = ei[j - 1]; ei[j - 1] = ti;
                    }
            }
        }
        int mynb = 0;
        #pragma unroll 1
        for (int r = 0; r < KNN; ++r) {
            float d = eh[0]; int i = ei[0];
            #pragma unroll
            for (int s2 = 1; s2 < 64; s2 <<= 1) {
                float d2 = __shfl_xor(d, s2); int i2 = __shfl_xor(i, s2);
                if (d2 < d || (d2 == d && i2 < i)) { d = d2; i = i2; }
            }
            if (lane == r) mynb = i;
            if (ei[0] == i) {
                #pragma unroll
                for (int j = 0; j < 15; ++j) { eh[j] = eh[j + 1]; ei[j] = ei[j + 1]; }
                eh[15] = 3.4e38f; ei[15] = 0x7fffffff;
            }
        }
        mynb = min(max(mynb, 0), NPTS - 1);
        if (lane < KNN) knnIdx[(size_t)p * KNN + lane] = mynb;
    }
}

// ---------------------------------------------------------------------------
// main: MFMA per-neighbor MLPs consuming knnIdx (proven verbatim R12/R14-R17).
// ---------------------------------------------------------------------------
__global__ __launch_bounds__(256) void LocalTransformer_80513456931527_kernel(
    const float* __restrict__ xyzp, const float* __restrict__ features,
    const float* __restrict__ Wp1,  const float* __restrict__ bp1,
    const float* __restrict__ bp2,  const float* __restrict__ bt1,
    const float* __restrict__ bt2,
    const float* __restrict__ Wa,   const float* __restrict__ ba,
    const float* __restrict__ qw, const float* __restrict__ kw,
    const float* __restrict__ vw,
    const unsigned short* __restrict__ fragw,
    const int* __restrict__ knnIdx,
    float* __restrict__ out)
{
    __shared__ __align__(16) float sBounce[4][16 * 68 + 4];

    int tid = threadIdx.x, w = tid >> 6, lane = tid & 63;
    int p = blockIdx.x * 4 + w;
    int b = p >> 13;
    float* bb = sBounce[w];

    int quad = lane >> 4, l15 = lane & 15;
    int mynb = knnIdx[(size_t)p * KNN + l15];
    mynb = min(max(mynb, 0), NPTS - 1);
    int nb_a = mynb;
    int nbm[4];
    #pragma unroll
    for (int r = 0; r < 4; ++r) nbm[r] = __shfl(mynb, quad * 4 + r);

    const float4 xq4 = *(const float4*)(xyzp + (size_t)p * 4);
    const float4 xn4 = *(const float4*)(xyzp + ((size_t)b * NPTS + nb_a) * 4);
    float rel0 = xq4.x - xn4.x, rel1 = xq4.y - xn4.y;
    float rel2 = xq4.z - xn4.z, rel3 = xq4.w - xn4.w;

    bf8_t pe1f[2];
    #pragma unroll
    for (int s = 0; s < 2; ++s) {
        int hb = s * 32 + quad * 8;
        float W0[8], W1[8], W2[8], W3[8], Bb[8];
        *(float4*)&W0[0] = *(const float4*)(Wp1 +       hb);
        *(float4*)&W0[4] = *(const float4*)(Wp1 +       hb + 4);
        *(float4*)&W1[0] = *(const float4*)(Wp1 +  64 + hb);
        *(float4*)&W1[4] = *(const float4*)(Wp1 +  64 + hb + 4);
        *(float4*)&W2[0] = *(const float4*)(Wp1 + 128 + hb);
        *(float4*)&W2[4] = *(const float4*)(Wp1 + 128 + hb + 4);
        *(float4*)&W3[0] = *(const float4*)(Wp1 + 192 + hb);
        *(float4*)&W3[4] = *(const float4*)(Wp1 + 192 + hb + 4);
        *(float4*)&Bb[0] = *(const float4*)(bp1 + hb);
        *(float4*)&Bb[4] = *(const float4*)(bp1 + hb + 4);
        #pragma unroll
        for (int j = 0; j < 8; ++j) {
            float a = Bb[j] + rel0 * W0[j] + rel1 * W1[j]
                            + rel2 * W2[j] + rel3 * W3[j];
            pe1f[s][j] = (short)f2b(fmaxf(a, 0.f));
        }
    }

    const bf8_t* BW = (const bf8_t*)fragw;
    f4_t pe2c[4];
    #pragma unroll
    for (int t = 0; t < 4; ++t) {
        f4_t acc = {0.f, 0.f, 0.f, 0.f};
        acc = MFMA16(pe1f[0], BW[0 * 512 + (0 * 4 + t) * 64 + lane], acc);
        acc = MFMA16(pe1f[1], BW[0 * 512 + (1 * 4 + t) * 64 + lane], acc);
        float bias = bp2[t * 16 + l15];
        #pragma unroll
        for (int r = 0; r < 4; ++r) acc[r] += bias;
        pe2c[t] = acc;
    }

    f4_t ainc[4], vpec[4];
    #pragma unroll
    for (int t = 0; t < 4; ++t) {
        float qv = qw[(size_t)p * HDIM + t * 16 + l15];
        #pragma unroll
        for (int r = 0; r < 4; ++r) {
            size_t nbo = ((size_t)b * NPTS + nbm[r]) * HDIM + t * 16 + l15;
            ainc[t][r] = qv - kw[nbo] + pe2c[t][r];
            vpec[t][r] = vw[nbo] + pe2c[t][r];
        }
    }

    #pragma unroll
    for (int t = 0; t < 4; ++t)
        #pragma unroll
        for (int r = 0; r < 4; ++r)
            bb[(quad * 4 + r) * 68 + t * 16 + l15] = ainc[t][r];
    asm volatile("s_waitcnt lgkmcnt(0)" ::: "memory");
    bf8_t af[2];
    #pragma unroll
    for (int s = 0; s < 2; ++s) {
        float tmp[8];
        *(float4*)&tmp[0] = *(const float4*)&bb[l15 * 68 + s * 32 + quad * 8];
        *(float4*)&tmp[4] = *(const float4*)&bb[l15 * 68 + s * 32 + quad * 8 + 4];
        #pragma unroll
        for (int j = 0; j < 8; ++j) af[s][j] = (short)f2b(tmp[j]);
    }

    f4_t t1c[4];
    #pragma unroll
    for (int t = 0; t < 4; ++t) {
        f4_t acc = {0.f, 0.f, 0.f, 0.f};
        acc = MFMA16(af[0], BW[1 * 512 + (0 * 4 + t) * 64 + lane], acc);
        acc = MFMA16(af[1], BW[1 * 512 + (1 * 4 + t) * 64 + lane], acc);
        float bias = bt1[t * 16 + l15];
        #pragma unroll
        for (int r = 0; r < 4; ++r) t1c[t][r] = fmaxf(acc[r] + bias, 0.f);
    }

    asm volatile("s_waitcnt lgkmcnt(0)" ::: "memory");
    #pragma unroll
    for (int t = 0; t < 4; ++t)
        #pragma unroll
        for (int r = 0; r < 4; ++r)
            bb[(quad * 4 + r) * 68 + t * 16 + l15] = t1c[t][r];
    asm volatile("s_waitcnt lgkmcnt(0)" ::: "memory");
    bf8_t tf[2];
    #pragma unroll
    for (int s = 0; s < 2; ++s) {
        float tmp[8];
        *(float4*)&tmp[0] = *(const float4*)&bb[l15 * 68 + s * 32 + quad * 8];
        *(float4*)&tmp[4] = *(const float4*)&bb[l15 * 68 + s * 32 + quad * 8 + 4];
        #pragma unroll
        for (int j = 0; j < 8; ++j) tf[s][j] = (short)f2b(tmp[j]);
    }

    f4_t lgc[4];
    #pragma unroll
    for (int t = 0; t < 4; ++t) {
        f4_t acc = {0.f, 0.f, 0.f, 0.f};
        acc = MFMA16(tf[0], BW[2 * 512 + (0 * 4 + t) * 64 + lane], acc);
        acc = MFMA16(tf[1], BW[2 * 512 + (1 * 4 + t) * 64 + lane], acc);
        float bias = bt2[t * 16 + l15];
        #pragma unroll
        for (int r = 0; r < 4; ++r) lgc[t][r] = (acc[r] + bias) * 0.125f;
    }

    float res[4];
    #pragma unroll
    for (int t = 0; t < 4; ++t) {
        float m0 = fmaxf(fmaxf(lgc[t][0], lgc[t][1]), fmaxf(lgc[t][2], lgc[t][3]));
        m0 = fmaxf(m0, __shfl_xor(m0, 16));
        m0 = fmaxf(m0, __shfl_xor(m0, 32));
        float e0 = fast_exp(lgc[t][0] - m0), e1 = fast_exp(lgc[t][1] - m0);
        float e2 = fast_exp(lgc[t][2] - m0), e3 = fast_exp(lgc[t][3] - m0);
        float sl = e0 + e1 + e2 + e3;
        float rl = e0 * vpec[t][0] + e1 * vpec[t][1]
                 + e2 * vpec[t][2] + e3 * vpec[t][3];
        sl += __shfl_xor(sl, 16); sl += __shfl_xor(sl, 32);
        rl += __shfl_xor(rl, 16); rl += __shfl_xor(rl, 32);
        res[t] = rl / sl;
    }

    float rh = (quad == 0) ? res[0] : (quad == 1) ? res[1]
             : (quad == 2) ? res[2] : res[3];
    float f = features[(size_t)p * HDIM + lane];
    float o = ba[lane];
    #pragma unroll 8
    for (int c = 0; c < 64; ++c) o += __shfl(rh, c) * Wa[c * 64 + lane];
    out[(size_t)p * HDIM + lane] = o + f;
}

// ---------------------------------------------------------------------------
extern "C" void kernel_launch(void* const* d_in, const int* in_sizes, int n_in,
                              void* d_out, int out_size, void* d_ws, size_t ws_size,
                              hipStream_t stream)
{
    (void)in_sizes; (void)n_in; (void)out_size; (void)ws_size;
    const float* xyzp     = (const float*)d_in[0];
    const float* features = (const float*)d_in[1];
    const float* Wk  = (const float*)d_in[2];
    const float* bk  = (const float*)d_in[3];
    const float* Wq  = (const float*)d_in[4];
    const float* Wks = (const float*)d_in[5];
    const float* Wv  = (const float*)d_in[6];
    const float* Wp1 = (const float*)d_in[7];
    const float* bp1 = (const float*)d_in[8];
    const float* Wp2 = (const float*)d_in[9];
    const float* bp2 = (const float*)d_in[10];
    const float* Wt1 = (const float*)d_in[11];
    const float* bt1 = (const float*)d_in[12];
    const float* Wt2 = (const float*)d_in[13];
    const float* bt2 = (const float*)d_in[14];
    const float* Wa  = (const float*)d_in[15];
    const float* ba  = (const float*)d_in[16];
    float* out = (float*)d_out;
    char* ws = (char*)d_ws;

    float* qw = (float*)(ws + OFF_QW);
    float* kw = (float*)(ws + OFF_KW);
    float* vw = (float*)(ws + OFF_VW);
    unsigned short* fragw = (unsigned short*)(ws + OFF_FRAG);
    int* knnIdx = (int*)(ws + OFF_KNN);
    int* fix    = (int*)(ws + OFF_FIX);

    hipMemsetAsync(fix, 0, 64, stream);   // zero worklist counter (capture-safe)
    prefrag_kernel<<<48, 256, 0, stream>>>(Wp2, Wt1, Wt2, fragw);
    proj_kernel<<<(2 * NPTS) / 16, 1024, 0, stream>>>(
        features, Wk, bk, Wq, Wks, Wv, qw, kw, vw);
    knn4_kernel<<<(2 * NPTS) / 16, 256, 0, stream>>>(xyzp, knnIdx, fix);
    knnfix_kernel<<<64, 256, 0, stream>>>(xyzp, fix, knnIdx);
    LocalTransformer_80513456931527_kernel<<<(2 * NPTS) / 4, 256, 0, stream>>>(
        xyzp, features, Wp1, bp1, bp2, bt1, bt2, Wa, ba,
        qw, kw, vw, fragw, knnIdx, out);
}